// Round 1
// baseline (853.718 us; speedup 1.0000x reference)
//
#include <hip/hip_runtime.h>
#include <hip/hip_fp16.h>
#include <stdint.h>

#define B_    64
#define T_    512
#define OBS_  128
#define FEAT_ 512
#define H_    256
#define G_    768
#define BT_   32768
#define NA_   10

struct __align__(16) H2x4 { __half2 a, b, c, d; };

__device__ __forceinline__ uint32_t h2u(__half2 h){ union{ __half2 h; uint32_t u; } c; c.h = h; return c.u; }
__device__ __forceinline__ __half2 u2h(uint32_t u){ union{ uint32_t u; __half2 h; } c; c.u = u; return c.h; }

// ---------------------------------------------------------------------------
// GEMM: C[M x N] = act( A[M x K] @ W[N x K]^T + bias )
// M-tile 128, N-tile 128, K-chunk 32. 256 threads, each 8x8 outputs.
// fp16-packed LDS tiles with granule XOR swizzle; half2 accumulators.
// ---------------------------------------------------------------------------
template<int KD, bool AHALF, bool RELU, bool SCATTER>
__global__ __launch_bounds__(256, 2)
void gemm_kernel(const float* __restrict__ Af, const __half2* __restrict__ Ah,
                 const float* __restrict__ W, const float* __restrict__ bias,
                 __half2* __restrict__ C)
{
    __shared__ H2x4 As[128 * 4];
    __shared__ H2x4 Bs[128 * 4];
    const int mt = blockIdx.x, nt = blockIdx.y;
    const int m0 = mt * 128, n0 = nt * 128;
    const int tid = threadIdx.x;
    const int r  = tid & 127;            // loader: tile row
    const int gp = (tid >> 7) * 2;       // loader: granule pair base (0 or 2)
    const int tr = tid >> 4, tc = tid & 15;  // compute: 16x16 thread grid

    __half2 acc[8][8];
    const __half2 hz = __float2half2_rn(0.0f);
    #pragma unroll
    for (int i = 0; i < 8; ++i)
        #pragma unroll
        for (int j = 0; j < 8; ++j) acc[i][j] = hz;

    for (int kc = 0; kc < KD / 32; ++kc) {
        __syncthreads();
        const int swz = (r >> 3) & 3;
        // ---- stage A tile ----
        if constexpr (!AHALF) {
            const float* src = Af + (size_t)(m0 + r) * KD + kc * 32 + gp * 8;
            #pragma unroll
            for (int g = 0; g < 2; ++g) {
                float4 f0 = ((const float4*)src)[g * 2 + 0];
                float4 f1 = ((const float4*)src)[g * 2 + 1];
                H2x4 gr;
                gr.a = __floats2half2_rn(f0.x, f0.y);
                gr.b = __floats2half2_rn(f0.z, f0.w);
                gr.c = __floats2half2_rn(f1.x, f1.y);
                gr.d = __floats2half2_rn(f1.z, f1.w);
                As[r * 4 + ((gp + g) ^ swz)] = gr;
            }
        } else {
            const H2x4* src = (const H2x4*)(Ah + (size_t)(m0 + r) * (KD / 2) + kc * 16 + gp * 4);
            #pragma unroll
            for (int g = 0; g < 2; ++g)
                As[r * 4 + ((gp + g) ^ swz)] = src[g];
        }
        // ---- stage B tile (W rows n0+r) ----
        {
            const float* src = W + (size_t)(n0 + r) * KD + kc * 32 + gp * 8;
            #pragma unroll
            for (int g = 0; g < 2; ++g) {
                float4 f0 = ((const float4*)src)[g * 2 + 0];
                float4 f1 = ((const float4*)src)[g * 2 + 1];
                H2x4 gr;
                gr.a = __floats2half2_rn(f0.x, f0.y);
                gr.b = __floats2half2_rn(f0.z, f0.w);
                gr.c = __floats2half2_rn(f1.x, f1.y);
                gr.d = __floats2half2_rn(f1.z, f1.w);
                Bs[r * 4 + ((gp + g) ^ swz)] = gr;
            }
        }
        __syncthreads();
        // ---- compute ----
        #pragma unroll
        for (int ks = 0; ks < 4; ++ks) {
            H2x4 Ag[8], Bg[8];
            #pragma unroll
            for (int i = 0; i < 8; ++i) Ag[i] = As[(tr * 8 + i) * 4 + (ks ^ (tr & 3))];
            #pragma unroll
            for (int j = 0; j < 8; ++j) Bg[j] = Bs[(tc * 8 + j) * 4 + (ks ^ (tc & 3))];
            #pragma unroll
            for (int i = 0; i < 8; ++i)
                #pragma unroll
                for (int j = 0; j < 8; ++j) {
                    acc[i][j] = __hfma2(Ag[i].a, Bg[j].a, acc[i][j]);
                    acc[i][j] = __hfma2(Ag[i].b, Bg[j].b, acc[i][j]);
                    acc[i][j] = __hfma2(Ag[i].c, Bg[j].c, acc[i][j]);
                    acc[i][j] = __hfma2(Ag[i].d, Bg[j].d, acc[i][j]);
                }
        }
    }
    // ---- epilogue ----
    constexpr int ROWH2 = SCATTER ? (G_ / 2) : (FEAT_ / 2);
    float bj[8];
    #pragma unroll
    for (int j = 0; j < 8; ++j) bj[j] = bias[n0 + tc * 8 + j];
    #pragma unroll
    for (int i = 0; i < 8; ++i) {
        int m = m0 + tr * 8 + i;
        float v[8];
        #pragma unroll
        for (int j = 0; j < 8; ++j) {
            v[j] = __low2float(acc[i][j]) + __high2float(acc[i][j]) + bj[j];
            if (RELU) v[j] = fmaxf(v[j], 0.0f);
        }
        size_t orow;
        if (SCATTER) { int bb = m >> 9, tt = m & 511; orow = (size_t)(tt * 64 + bb); }
        else orow = (size_t)m;
        H2x4 o;
        o.a = __floats2half2_rn(v[0], v[1]);
        o.b = __floats2half2_rn(v[2], v[3]);
        o.c = __floats2half2_rn(v[4], v[5]);
        o.d = __floats2half2_rn(v[6], v[7]);
        *((H2x4*)(C + orow * ROWH2 + (n0 / 2 + tc * 4))) = o;
    }
}

// ---------------------------------------------------------------------------
// GRU scan: one block per batch, 512 threads. W_hh fp16 in registers
// (thread (q, r1) holds rows r1+j*128, k-slice [q*64, q*64+64)).
// h broadcast from LDS as packed half2. Mask==0 steps skip the dot phase.
// ---------------------------------------------------------------------------
__global__ __launch_bounds__(512, 2)
void gru_scan(const __half2* __restrict__ gx,   // (T*B) x 384 h2  (t,b,g)
              const float* __restrict__ Whh,    // 768 x 256
              const float* __restrict__ bhh,    // 768
              const int* __restrict__ masks,    // B x (T-1)
              const float* __restrict__ h0,     // B x 256
              float* __restrict__ hs)           // (B*T) x 256
{
    __shared__ __align__(16) uint32_t h2buf[128];
    __shared__ float part[3072];
    const int b = blockIdx.x;
    const int tid = threadIdx.x;
    const int q = tid >> 7;        // k-quarter 0..3
    const int r1 = tid & 127;

    // weight registers: 6 outputs x 32 half2 (64 k each)
    __half2 w[6][32];
    #pragma unroll
    for (int j = 0; j < 6; ++j) {
        const float2* wr = (const float2*)(Whh + (size_t)(r1 + j * 128) * 256 + q * 64);
        #pragma unroll
        for (int kk = 0; kk < 32; ++kk) {
            float2 f = wr[kk];
            w[j][kk] = __floats2half2_rn(f.x, f.y);
        }
    }

    float bh_r = 0.f, bh_z = 0.f, bh_n = 0.f, hreg = 0.f;
    if (tid < 256) {
        bh_r = bhh[tid];
        bh_z = bhh[tid + 256];
        bh_n = bhh[tid + 512];
        hreg = h0[b * 256 + tid];
    }
    if (tid < 128) {
        float2 f = ((const float2*)(h0 + b * 256))[tid];
        h2buf[tid] = h2u(__floats2half2_rn(f.x, f.y));
    }
    __syncthreads();

    const uint4* h2v = (const uint4*)h2buf;
    const __half2 hz = __float2half2_rn(0.0f);

    for (int s = 0; s < T_; ++s) {
        const int m = (s == 0) ? 1 : masks[b * (T_ - 1) + (s - 1)];
        // prefetch gx for this step (hidden under the dots)
        float gxr = 0.f, gxz = 0.f, gxn = 0.f;
        if (tid < 256) {
            const __half* grow = (const __half*)(gx + (size_t)(s * 64 + b) * 384);
            gxr = __half2float(grow[tid]);
            gxz = __half2float(grow[tid + 256]);
            gxn = __half2float(grow[tid + 512]);
        }
        if (m) {
            __half2 acc0 = hz, acc1 = hz, acc2 = hz, acc3 = hz, acc4 = hz, acc5 = hz;
            #pragma unroll
            for (int kb = 0; kb < 8; ++kb) {
                uint4 hv = h2v[q * 8 + kb];
                __half2 e0 = u2h(hv.x), e1 = u2h(hv.y), e2 = u2h(hv.z), e3 = u2h(hv.w);
                acc0 = __hfma2(w[0][kb*4+0], e0, acc0); acc0 = __hfma2(w[0][kb*4+1], e1, acc0);
                acc0 = __hfma2(w[0][kb*4+2], e2, acc0); acc0 = __hfma2(w[0][kb*4+3], e3, acc0);
                acc1 = __hfma2(w[1][kb*4+0], e0, acc1); acc1 = __hfma2(w[1][kb*4+1], e1, acc1);
                acc1 = __hfma2(w[1][kb*4+2], e2, acc1); acc1 = __hfma2(w[1][kb*4+3], e3, acc1);
                acc2 = __hfma2(w[2][kb*4+0], e0, acc2); acc2 = __hfma2(w[2][kb*4+1], e1, acc2);
                acc2 = __hfma2(w[2][kb*4+2], e2, acc2); acc2 = __hfma2(w[2][kb*4+3], e3, acc2);
                acc3 = __hfma2(w[3][kb*4+0], e0, acc3); acc3 = __hfma2(w[3][kb*4+1], e1, acc3);
                acc3 = __hfma2(w[3][kb*4+2], e2, acc3); acc3 = __hfma2(w[3][kb*4+3], e3, acc3);
                acc4 = __hfma2(w[4][kb*4+0], e0, acc4); acc4 = __hfma2(w[4][kb*4+1], e1, acc4);
                acc4 = __hfma2(w[4][kb*4+2], e2, acc4); acc4 = __hfma2(w[4][kb*4+3], e3, acc4);
                acc5 = __hfma2(w[5][kb*4+0], e0, acc5); acc5 = __hfma2(w[5][kb*4+1], e1, acc5);
                acc5 = __hfma2(w[5][kb*4+2], e2, acc5); acc5 = __hfma2(w[5][kb*4+3], e3, acc5);
            }
            part[r1 + 0 * 128 + q * 768] = __low2float(acc0) + __high2float(acc0);
            part[r1 + 1 * 128 + q * 768] = __low2float(acc1) + __high2float(acc1);
            part[r1 + 2 * 128 + q * 768] = __low2float(acc2) + __high2float(acc2);
            part[r1 + 3 * 128 + q * 768] = __low2float(acc3) + __high2float(acc3);
            part[r1 + 4 * 128 + q * 768] = __low2float(acc4) + __high2float(acc4);
            part[r1 + 5 * 128 + q * 768] = __low2float(acc5) + __high2float(acc5);
            __syncthreads();
        }
        // combine + gates (threads 0..255, one h element each)
        if (tid < 256) {
            float ghr = bh_r, ghz = bh_z, ghn = bh_n;
            if (m) {
                ghr += part[tid]       + part[tid + 768]       + part[tid + 1536]       + part[tid + 2304];
                ghz += part[tid + 256] + part[tid + 256 + 768] + part[tid + 256 + 1536] + part[tid + 256 + 2304];
                ghn += part[tid + 512] + part[tid + 512 + 768] + part[tid + 512 + 1536] + part[tid + 512 + 2304];
            }
            const float hp = m ? hreg : 0.0f;
            const float rg = 1.0f / (1.0f + exp2f(-(gxr + ghr) * 1.44269504f));
            const float zg = 1.0f / (1.0f + exp2f(-(gxz + ghz) * 1.44269504f));
            const float nin = gxn + rg * ghn;
            const float e2x = exp2f(nin * 2.885390082f);
            const float ng = 1.0f - 2.0f / (e2x + 1.0f);      // tanh(nin)
            const float hnew = (1.0f - zg) * ng + zg * hp;
            hreg = hnew;
            hs[(size_t)(b * 512 + s) * 256 + tid] = hnew;
            const float other = __shfl_xor(hnew, 1);
            if ((tid & 1) == 0)
                h2buf[tid >> 1] = h2u(__floats2half2_rn(hnew, other));
        }
        __syncthreads();
    }
}

// ---------------------------------------------------------------------------
// Heads: one wave per output row. 11 dots of 256, butterfly reduce,
// stable log_softmax, entropy, action gather.
// ---------------------------------------------------------------------------
__global__ __launch_bounds__(256)
void heads_kernel(const float* __restrict__ hs, const float* __restrict__ Wa,
                  const float* __restrict__ ba, const float* __restrict__ Wc,
                  const float* __restrict__ bc, const int* __restrict__ action,
                  float* __restrict__ out)
{
    const int wid = threadIdx.x >> 6, lane = threadIdx.x & 63;
    const int row = blockIdx.x * 4 + wid;
    const float4 hv = ((const float4*)(hs + (size_t)row * 256))[lane];
    float sums[11];
    #pragma unroll
    for (int n = 0; n < 11; ++n) {
        const float* wrow = (n < 10) ? (Wa + n * 256) : Wc;
        const float4 wv = ((const float4*)wrow)[lane];
        sums[n] = hv.x * wv.x + hv.y * wv.y + hv.z * wv.z + hv.w * wv.w;
    }
    #pragma unroll
    for (int n = 0; n < 11; ++n) {
        float v = sums[n];
        #pragma unroll
        for (int off = 32; off; off >>= 1) v += __shfl_xor(v, off);
        sums[n] = v;
    }
    float logits[10];
    #pragma unroll
    for (int n = 0; n < 10; ++n) logits[n] = sums[n] + ba[n];
    const float value = sums[10] + bc[0];
    float mx = logits[0];
    #pragma unroll
    for (int n = 1; n < 10; ++n) mx = fmaxf(mx, logits[n]);
    float ssum = 0.f, sdot = 0.f;
    #pragma unroll
    for (int n = 0; n < 10; ++n) {
        float d = logits[n] - mx;
        float e = exp2f(d * 1.44269504f);
        ssum += e; sdot += e * d;
    }
    const float lns = logf(ssum);
    const float lse = mx + lns;
    const float entropy = lns - sdot / ssum;
    const int a = action[row];
    float la = 0.f;
    #pragma unroll
    for (int n = 0; n < 10; ++n) la = (n == a) ? logits[n] : la;
    if (lane == 0) {
        out[row] = value;
        out[BT_ + row] = la - lse;
        out[2 * BT_ + row] = entropy;
    }
}

// ---------------------------------------------------------------------------
extern "C" void kernel_launch(void* const* d_in, const int* in_sizes, int n_in,
                              void* d_out, int out_size, void* d_ws, size_t ws_size,
                              hipStream_t stream)
{
    const float* obs    = (const float*)d_in[0];
    const int*   action = (const int*)d_in[1];
    const int*   masks  = (const int*)d_in[2];
    const float* h0     = (const float*)d_in[3];
    const float* W1     = (const float*)d_in[4];
    const float* b1     = (const float*)d_in[5];
    const float* Wih    = (const float*)d_in[6];
    const float* Whh    = (const float*)d_in[7];
    const float* bih    = (const float*)d_in[8];
    const float* bhh    = (const float*)d_in[9];
    const float* Wa     = (const float*)d_in[10];
    const float* ba     = (const float*)d_in[11];
    const float* Wc     = (const float*)d_in[12];
    const float* bc     = (const float*)d_in[13];
    float* out = (float*)d_out;

    char* ws = (char*)d_ws;
    __half2* feat = (__half2*)ws;                                   // 33,554,432 B
    __half2* gx   = (__half2*)(ws + 33554432);                      // 50,331,648 B
    float*   hs   = (float*)(ws + 33554432 + 50331648);             // 33,554,432 B

    // feat = relu(obs @ W1^T + b1)
    gemm_kernel<128, false, true,  false><<<dim3(256, 4), 256, 0, stream>>>(obs, nullptr, W1, b1, feat);
    // gx(t,b,g) = feat @ W_ih^T + b_ih
    gemm_kernel<512, true,  false, true ><<<dim3(256, 6), 256, 0, stream>>>(nullptr, feat, Wih, bih, gx);
    // recurrence
    gru_scan<<<64, 512, 0, stream>>>(gx, Whh, bhh, masks, h0, hs);
    // heads
    heads_kernel<<<8192, 256, 0, stream>>>(hs, Wa, ba, Wc, bc, action, out);
}